// Round 8
// baseline (128.742 us; speedup 1.0000x reference)
//
#include <hip/hip_runtime.h>
#include <hip/hip_bf16.h>
#include <stdint.h>

#define BB 16
#define CC 128
#define HH 64
#define WW 64
#define LL 4096
#define SS 16
#define NCH 64
#define CT 64

typedef __attribute__((ext_vector_type(4))) float f32x4;
typedef __attribute__((ext_vector_type(8))) short short8;
typedef __attribute__((ext_vector_type(4))) unsigned int u32x4;

#define AS1 __attribute__((address_space(1)))
#define AS3 __attribute__((address_space(3)))

__device__ __forceinline__ float bf2f(unsigned short u) {
    union { unsigned int i; float f; } v;
    v.i = ((unsigned int)u) << 16;
    return v.f;
}
__device__ __forceinline__ unsigned short f2bf(float f) {
    union { float f; unsigned int i; } v;
    v.f = f;
    unsigned int x = v.i;
    return (unsigned short)((x + 0x7fffu + ((x >> 16) & 1u)) >> 16);
}
__device__ __forceinline__ float fexp2(float x) { return __builtin_amdgcn_exp2f(x); }

// ---------------- K0: x-transpose (blocks 0..2047) + weight transforms (blocks 2048..) ----------------
__global__ __launch_bounds__(256) void k0(const float* __restrict__ x, unsigned short* __restrict__ xT,
                                          const float* __restrict__ conv_w, const float* __restrict__ dt_w,
                                          const float* __restrict__ A, const float* __restrict__ Dv,
                                          const float* __restrict__ g1w, const float* __restrict__ g2w,
                                          short* __restrict__ wf, short* __restrict__ wdtf,
                                          float* __restrict__ An, float* __restrict__ An2, float* __restrict__ Dp,
                                          float* __restrict__ pooled, float* __restrict__ g1wT, float* __restrict__ g2wT) {
    __shared__ float lt[64][65];
    int bid = blockIdx.x;
    int tid = threadIdx.x;
    if (bid < 2048) {
        int b = bid >> 7, rem = bid & 127;
        int tt = rem >> 1, ct = rem & 1;
        int t0 = tt * 64, c0 = ct * 64;
        int colr = tid & 63, rowb = tid >> 6;
#pragma unroll
        for (int r = 0; r < 16; ++r) {
            int row = rowb + r * 4;
            lt[row][colr] = x[(size_t)(b * CC + c0 + row) * LL + t0 + colr];
        }
        __syncthreads();
#pragma unroll
        for (int r = 0; r < 16; ++r) {
            int trow = rowb + r * 4;
            xT[((size_t)b * LL + t0 + trow) * CC + c0 + colr] = f2bf(lt[colr][trow]);
        }
        return;
    }
    int idx = (bid - 2048) * 256 + tid;
    if (idx < 18432) {
        int lane = idx & 63, fr = idx >> 6;
        int nfg = fr & 7, ks = (fr >> 3) & 3, tp = fr >> 5;
        int dy = tp / 3, dx = tp % 3;
        int cout = nfg * 16 + (lane & 15);
        int cin0 = ks * 32 + (lane >> 4) * 8;
        short8 v;
#pragma unroll
        for (int j = 0; j < 8; ++j)
            v[j] = (short)f2bf(conv_w[((cout * CC + cin0 + j) * 3 + dy) * 3 + dx]);
        *(short8*)(wf + (size_t)idx * 8) = v;
    } else if (idx < 20480) {
        int i2 = idx - 18432;
        int lane = i2 & 63, fr = i2 >> 6;
        int nfg = fr & 7, ks = fr >> 3;
        int o = nfg * 16 + (lane & 15);
        int c0 = ks * 32 + (lane >> 4) * 8;
        short8 v;
#pragma unroll
        for (int j = 0; j < 8; ++j) v[j] = (short)f2bf(dt_w[o * CC + c0 + j]);
        *(short8*)(wdtf + (size_t)i2 * 8) = v;
    } else if (idx < 22528) {
        int i3 = idx - 20480;
        float a = -expf(A[i3]);
        An[i3] = a;
        An2[i3] = a * 1.4426950408889634f;
    } else if (idx < 22656) {
        int c = idx - 22528;
        Dp[c] = expf(Dv[c]);
    } else if (idx < 24704) {
        pooled[idx - 22656] = 0.f;
    } else if (idx < 41088) {
        int i = idx - 24704;
        int c = i >> 7, o = i & 127;
        g1wT[i] = g1w[o * 128 + c];
    } else if (idx < 57472) {
        int i = idx - 41088;
        int c = i >> 7, o = i & 127;
        g2wT[i] = g2w[o * 128 + c];
    }
}

// ---------------- K1: 3x3 conv via MFMA implicit GEMM ----------------
__global__ __launch_bounds__(256) void k1(const unsigned short* __restrict__ xT,
                                          const short* __restrict__ wf,
                                          const float* __restrict__ conv_b,
                                          unsigned short* __restrict__ convT,
                                          float* __restrict__ pooled) {
    __shared__ __align__(16) unsigned short slab[3 * 66 * 128];  // 50688 B
    int bid = blockIdx.x;
    int b = bid >> 6, h = bid & 63;
    int tid = threadIdx.x;
    int wave = tid >> 6, lane = tid & 63;

    if (tid < 96) {
        int dy = tid >> 5, r = (tid >> 4) & 1, j = tid & 15;
        u32x4 z = {0, 0, 0, 0};
        *(u32x4*)((char*)slab + dy * 16896 + (r ? 16640 : 0) + j * 16) = z;
    }
#pragma unroll
    for (int dy = 0; dy < 3; ++dy) {
        int hs = h + dy - 1;
        char* slabdy = (char*)slab + dy * 16896;
        if (hs >= 0 && hs < HH) {
            const char* src = (const char*)xT + (size_t)(b * LL + hs * 64) * 256;
#pragma unroll
            for (int i = 0; i < 4; ++i) {
                unsigned int Xbase = 256u + (unsigned)i * 4096u + (unsigned)wave * 1024u;
                unsigned int X = Xbase + (unsigned)lane * 16u;
                unsigned int tok = X >> 8;
                unsigned int srcoff = ((X & ~255u) - 256u) | ((X & 255u) ^ ((tok & 7u) << 4));
                __builtin_amdgcn_global_load_lds((const AS1 unsigned int*)(src + srcoff),
                                                 (AS3 unsigned int*)(slabdy + Xbase), 16, 0, 0);
            }
        } else {
            u32x4 z = {0, 0, 0, 0};
#pragma unroll
            for (int i = 0; i < 4; ++i)
                *(u32x4*)(slabdy + 256 + tid * 64 + i * 16) = z;
        }
    }
    __syncthreads();

    int lm = lane & 15, lg = lane >> 4;
    f32x4 acc[4][2];
#pragma unroll
    for (int m = 0; m < 4; ++m)
#pragma unroll
        for (int n = 0; n < 2; ++n) acc[m][n] = (f32x4){0.f, 0.f, 0.f, 0.f};

#pragma unroll
    for (int tp = 0; tp < 9; ++tp) {
        int dy = tp / 3, dx = tp % 3;
        const char* slabdy = (const char*)slab + dy * 16896;
#pragma unroll
        for (int ks = 0; ks < 4; ++ks) {
            short8 bf0 = *(const short8*)(wf + ((size_t)(((tp * 4 + ks) * 8) + wave * 2 + 0) * 64 + lane) * 8);
            short8 bf1 = *(const short8*)(wf + ((size_t)(((tp * 4 + ks) * 8) + wave * 2 + 1) * 64 + lane) * 8);
#pragma unroll
            for (int mf = 0; mf < 4; ++mf) {
                int tok = mf * 16 + lm + dx;
                unsigned int off = (unsigned)((tok * 256 + ks * 64 + lg * 16) ^ ((tok & 7) << 4));
                short8 af = *(const short8*)(slabdy + off);
                acc[mf][0] = __builtin_amdgcn_mfma_f32_16x16x32_bf16(af, bf0, acc[mf][0], 0, 0, 0);
                acc[mf][1] = __builtin_amdgcn_mfma_f32_16x16x32_bf16(af, bf1, acc[mf][1], 0, 0, 0);
            }
        }
    }

    int n0w = wave * 32;
    size_t tokbase = (size_t)(b * LL + h * 64);
    float psum[2] = {0.f, 0.f};
#pragma unroll
    for (int nf = 0; nf < 2; ++nf) {
        int n = n0w + nf * 16 + lm;
        float bias = conv_b[n];
#pragma unroll
        for (int mf = 0; mf < 4; ++mf)
#pragma unroll
            for (int r = 0; r < 4; ++r) {
                int w = mf * 16 + lg * 4 + r;
                float v = acc[mf][nf][r] + bias;
                convT[(tokbase + w) * CC + n] = f2bf(v);
                psum[nf] += v;
            }
    }
#pragma unroll
    for (int nf = 0; nf < 2; ++nf) {
        float s = psum[nf];
        s += __shfl_xor(s, 16);
        s += __shfl_xor(s, 32);
        if (lane < 16) atomicAdd(&pooled[b * CC + n0w + nf * 16 + lane], s);
    }
}

// ---------------- K3: gate (per-block) + dt GEMM + sigmoid + fused scan phase-1 ----------------
__global__ __launch_bounds__(256) void k3(const unsigned short* __restrict__ convT,
                                          const short* __restrict__ wdtf,
                                          const float* __restrict__ pooled,
                                          const float* __restrict__ g1wT, const float* __restrict__ g1b,
                                          const float* __restrict__ g2wT, const float* __restrict__ g2b,
                                          float* __restrict__ gate,
                                          const float* __restrict__ dt_b,
                                          const float* __restrict__ An2,
                                          unsigned short* __restrict__ dtT,
                                          float* __restrict__ hend, float* __restrict__ decay) {
    __shared__ __align__(16) unsigned short albuf[128 * 128];   // 32KB gated-x (swizzled)
    __shared__ __align__(16) unsigned short dtl[128 * 136];     // 34KB dt (stride-136)
    __shared__ float gl[128];
    float* meanr = (float*)dtl;        // alias: dead before dtl's first real use
    float* garr  = ((float*)dtl) + 128;
    int bid = blockIdx.x;
    int b = bid >> 5, tile = bid & 31, t0 = tile * 128;
    int tid = threadIdx.x;
    int wave = tid >> 6, lane = tid & 63;

    // per-block gate compute (deterministic, identical across tiles of same b)
    if (tid < 128) meanr[tid] = pooled[b * CC + tid] * (1.f / 4096.f);
    __syncthreads();
    if (tid < 128) {
        float acc = g1b[tid];
        for (int c = 0; c < 128; ++c) acc += meanr[c] * g1wT[c * 128 + tid];
        garr[tid] = fmaxf(acc, 0.f);
    }
    __syncthreads();
    if (tid < 128) {
        float acc2 = g2b[tid];
        for (int c = 0; c < 128; ++c) acc2 += garr[c] * g2wT[c * 128 + tid];
        float gv = __builtin_amdgcn_rcpf(1.f + fexp2(-1.4426950408889634f * acc2));
        gl[tid] = gv;
        if (tile == 0) gate[b * CC + tid] = gv;
    }
    __syncthreads();

    const char* srcb = (const char*)convT + (size_t)(b * LL + t0) * 256;
#pragma unroll
    for (int i = 0; i < 8; ++i) {
        unsigned int byteoff = (unsigned)((i * 256 + tid) * 16);
        unsigned int tok = byteoff >> 8;
        unsigned int inner = byteoff & 255u;
        int c8 = (int)(inner >> 1);
        short8 v = *(const short8*)(srcb + (size_t)tok * 256 + inner);
#pragma unroll
        for (int j = 0; j < 8; ++j) {
            float f = bf2f((unsigned short)v[j]) * gl[c8 + j];
            v[j] = (short)f2bf(f);
        }
        *(short8*)((char*)albuf + (byteoff ^ ((tok & 7u) << 4))) = v;
    }
    __syncthreads();

    int lm = lane & 15, lg = lane >> 4;
    f32x4 acc[8][2];
#pragma unroll
    for (int m = 0; m < 8; ++m)
#pragma unroll
        for (int n = 0; n < 2; ++n) acc[m][n] = (f32x4){0.f, 0.f, 0.f, 0.f};
#pragma unroll
    for (int ks = 0; ks < 4; ++ks) {
        short8 bf0 = *(const short8*)(wdtf + ((size_t)((ks * 8) + wave * 2 + 0) * 64 + lane) * 8);
        short8 bf1 = *(const short8*)(wdtf + ((size_t)((ks * 8) + wave * 2 + 1) * 64 + lane) * 8);
#pragma unroll
        for (int mf = 0; mf < 8; ++mf) {
            int tok = mf * 16 + lm;
            unsigned int off = (unsigned)((tok * 256 + ks * 64 + lg * 16) ^ ((tok & 7) << 4));
            short8 af = *(const short8*)((const char*)albuf + off);
            acc[mf][0] = __builtin_amdgcn_mfma_f32_16x16x32_bf16(af, bf0, acc[mf][0], 0, 0, 0);
            acc[mf][1] = __builtin_amdgcn_mfma_f32_16x16x32_bf16(af, bf1, acc[mf][1], 0, 0, 0);
        }
    }
    __syncthreads();
#pragma unroll
    for (int nf = 0; nf < 2; ++nf) {
        int o = wave * 32 + nf * 16 + lm;
        float zb = dt_b[o];
#pragma unroll
        for (int mf = 0; mf < 8; ++mf)
#pragma unroll
            for (int r = 0; r < 4; ++r) {
                int tok = mf * 16 + lg * 4 + r;
                float z = acc[mf][nf][r] + zb;
                float d = __builtin_amdgcn_rcpf(1.f + fexp2(-1.4426950408889634f * z));
                unsigned short ub = f2bf(d);
                dtT[(size_t)(b * LL + t0 + tok) * CC + o] = ub;
                dtl[tok * 136 + o] = ub;
            }
    }
    __syncthreads();

    // fused scan phase-1: 2 chunks x 128 channels; x from albuf (gated), dt from dtl
    int half = tid >> 7, c = tid & 127;
    int ch = tile * 2 + half;
    float a2[SS], h[SS];
#pragma unroll
    for (int s = 0; s < SS; ++s) {
        a2[s] = An2[c * SS + s];
        h[s] = 0.f;
    }
    float sdt = 0.f;
#pragma unroll 4
    for (int t = 0; t < CT; ++t) {
        int tokb = half * 64 + t;
        unsigned int xoff = ((unsigned)(tokb * 256 + c * 2)) ^ (((unsigned)tokb & 7u) << 4);
        float x = bf2f(*(const unsigned short*)((const char*)albuf + xoff));
        float d = bf2f(dtl[tokb * 136 + c]);
        sdt += d;
#pragma unroll
        for (int s = 0; s < SS; ++s) h[s] = h[s] * fexp2(a2[s] * d) + x;
    }
    size_t base = ((size_t)(b * NCH + ch) * CC + c) * SS;
#pragma unroll
    for (int q = 0; q < 4; ++q) {
        f32x4 hv, dv;
#pragma unroll
        for (int j = 0; j < 4; ++j) {
            hv[j] = h[q * 4 + j];
            dv[j] = fexp2(a2[q * 4 + j] * sdt);
        }
        *(f32x4*)(hend + base + q * 4) = hv;
        *(f32x4*)(decay + base + q * 4) = dv;
    }
}

// ---------------- K5: sequential chunk combine ----------------
__global__ __launch_bounds__(256) void k5(const float* __restrict__ hend, const float* __restrict__ decay,
                                          float* __restrict__ H0) {
    int idx = blockIdx.x * 256 + threadIdx.x;  // 32768
    int b = idx >> 11, rem = idx & 2047;
    float Hv = 0.f;
    for (int k = 0; k < NCH; ++k) {
        size_t base = (size_t)(b * NCH + k) * 2048 + rem;
        H0[base] = Hv;
        Hv = hend[base] + Hv * decay[base];
    }
}

// ---------------- K6: scan phase 2, s-split, xin reg-prefetch overlaps scan ----------------
__global__ __launch_bounds__(256, 4) void k6(const unsigned short* __restrict__ convT,
                                             const unsigned short* __restrict__ dtT,
                                             const float* __restrict__ gate,
                                             const float* __restrict__ Antab,
                                             const float* __restrict__ An2tab,
                                             const float* __restrict__ Dp,
                                             const float* __restrict__ H0,
                                             const float* __restrict__ xin,
                                             float* __restrict__ out) {
    __shared__ unsigned short ylds[128][66];                // 16.9KB
    int bid = blockIdx.x;
    int b = bid >> 6, ch = bid & 63;
    int tid = threadIdx.x;                 // 256
    int wave = tid >> 6, lane = tid & 63;
    int t0 = ch * CT;
    int c = wave * 32 + (lane & 31);       // channel 0..127
    int shalf = lane >> 5;                 // 0: s=0..7, 1: s=8..15
    int s0 = shalf * 8;

    // ---- prefetch xin for the output phase FIRST (longest distance-to-use;
    // the 33.6MB read streams under the scan compute, vmcnt waited after barrier) ----
    int tt = tid & 63, wq = tid >> 6;
    size_t outbase = (size_t)b * CC * LL + t0 + tt;
    float xid[32];
#pragma unroll
    for (int rr = 0; rr < 32; ++rr)
        xid[rr] = xin[outbase + (size_t)(rr * 4 + wq) * LL];

    float a2[8], an[8], h[8];
#pragma unroll
    for (int q = 0; q < 2; ++q) {
        f32x4 av = *(const f32x4*)(An2tab + c * SS + s0 + q * 4);
        f32x4 nv = *(const f32x4*)(Antab + c * SS + s0 + q * 4);
#pragma unroll
        for (int j = 0; j < 4; ++j) { a2[q * 4 + j] = av[j]; an[q * 4 + j] = nv[j]; }
    }
    size_t hbase = ((size_t)(b * NCH + ch) * CC + c) * SS + s0;
#pragma unroll
    for (int q = 0; q < 2; ++q) {
        f32x4 hv = *(const f32x4*)(H0 + hbase + q * 4);
#pragma unroll
        for (int j = 0; j < 4; ++j) h[q * 4 + j] = hv[j];
    }
    float g = gate[b * CC + c];
    float dpc = (shalf == 0) ? Dp[c] : 0.f;
    const unsigned short* xp = convT + (size_t)(b * LL + t0) * CC + c;
    const unsigned short* dp = dtT + (size_t)(b * LL + t0) * CC + c;

#pragma unroll 4
    for (int t = 0; t < CT; ++t) {
        float x = bf2f(xp[t * CC]) * g;
        float d = bf2f(dp[t * CC]);
        float y0 = dpc * x, y1 = 0.f;
#pragma unroll
        for (int s = 0; s < 8; ++s) {
            h[s] = h[s] * fexp2(a2[s] * d) + x;
            if (s & 1) y1 += h[s] * an[s]; else y0 += h[s] * an[s];
        }
        float yp = y0 + y1;
        float yo = yp + __shfl_xor(yp, 32);
        if (shalf == 0) ylds[c][t] = f2bf(yo);
    }
    __syncthreads();

    // output phase: write-only (xin already in registers)
    size_t outg = outbase;
#pragma unroll 4
    for (int rr = 0; rr < 32; ++rr) {
        int row = rr * 4 + wq;
        out[outg + (size_t)row * LL] = bf2f(ylds[row][tt]) + xid[rr];
    }
}

extern "C" void kernel_launch(void* const* d_in, const int* in_sizes, int n_in,
                              void* d_out, int out_size, void* d_ws, size_t ws_size,
                              hipStream_t stream) {
    const float* x      = (const float*)d_in[0];
    const float* conv_w = (const float*)d_in[1];
    const float* conv_b = (const float*)d_in[2];
    const float* dt_w   = (const float*)d_in[3];
    const float* dt_b   = (const float*)d_in[4];
    const float* A      = (const float*)d_in[5];
    const float* D      = (const float*)d_in[6];
    const float* g1w    = (const float*)d_in[7];
    const float* g1b    = (const float*)d_in[8];
    const float* g2w    = (const float*)d_in[9];
    const float* g2b    = (const float*)d_in[10];

    char* ws = (char*)d_ws;
    unsigned short* xT    = (unsigned short*)(ws + 0);          // 16.78 MB (k0->k1)
    float* hend           = (float*)(ws + 0);                   //  8.39 MB (after k1, overlays xT)
    float* decay          = (float*)(ws + 8388608);             //  8.39 MB
    unsigned short* convT = (unsigned short*)(ws + 16777216);   // 16.78 MB
    unsigned short* dtT   = (unsigned short*)(ws + 33554432);   // 16.78 MB
    float* H0             = (float*)(ws + 50331648);            //  8.39 MB (written by k5)
    float* g1wT           = (float*)(ws + 50331648);            //  64 KB (k0->k3; overlaid by H0 after k3)
    float* g2wT           = (float*)(ws + 50397184);            //  64 KB (k0->k3; overlaid by H0 after k3)
    short* wf             = (short*)(ws + 58720256);            //  294912 B
    short* wdtf           = (short*)(ws + 59015168);            //  32768 B
    float* pooled         = (float*)(ws + 59047936);            //  8192 B
    float* gate           = (float*)(ws + 59056128);            //  8192 B
    float* Antab          = (float*)(ws + 59064320);            //  8192 B
    float* An2tab         = (float*)(ws + 59072512);            //  8192 B
    float* Dp             = (float*)(ws + 59080704);            //  512 B
    float* outp           = (float*)d_out;

    hipLaunchKernelGGL(k0, dim3(2273), dim3(256), 0, stream, x, xT, conv_w, dt_w, A, D, g1w, g2w,
                       wf, wdtf, Antab, An2tab, Dp, pooled, g1wT, g2wT);
    hipLaunchKernelGGL(k1, dim3(1024), dim3(256), 0, stream, xT, wf, conv_b, convT, pooled);
    hipLaunchKernelGGL(k3, dim3(512), dim3(256), 0, stream, convT, wdtf, pooled, g1wT, g1b, g2wT, g2b,
                       gate, dt_b, An2tab, dtT, hend, decay);
    hipLaunchKernelGGL(k5, dim3(128), dim3(256), 0, stream, hend, decay, H0);
    hipLaunchKernelGGL(k6, dim3(1024), dim3(256), 0, stream, convT, dtT, gate, Antab, An2tab, Dp, H0, x, outp);
}

// Round 9
// 121.546 us; speedup vs baseline: 1.0592x; 1.0592x over previous
//
#include <hip/hip_runtime.h>
#include <hip/hip_bf16.h>
#include <stdint.h>

#define BB 16
#define CC 128
#define HH 64
#define WW 64
#define LL 4096
#define SS 16
#define NCH 64
#define CT 64

typedef __attribute__((ext_vector_type(2))) float f32x2;
typedef __attribute__((ext_vector_type(4))) float f32x4;
typedef __attribute__((ext_vector_type(8))) short short8;
typedef __attribute__((ext_vector_type(4))) unsigned int u32x4;

#define AS1 __attribute__((address_space(1)))
#define AS3 __attribute__((address_space(3)))

__device__ __forceinline__ float bf2f(unsigned short u) {
    union { unsigned int i; float f; } v;
    v.i = ((unsigned int)u) << 16;
    return v.f;
}
__device__ __forceinline__ float asf(unsigned int u) {
    union { unsigned int i; float f; } v;
    v.i = u;
    return v.f;
}
__device__ __forceinline__ unsigned short f2bf(float f) {
    union { float f; unsigned int i; } v;
    v.f = f;
    unsigned int x = v.i;
    return (unsigned short)((x + 0x7fffu + ((x >> 16) & 1u)) >> 16);
}
__device__ __forceinline__ float fexp2(float x) { return __builtin_amdgcn_exp2f(x); }

// ---------------- K0: x-transpose (blocks 0..2047) + weight transforms (blocks 2048..) ----------------
__global__ __launch_bounds__(256) void k0(const float* __restrict__ x, unsigned short* __restrict__ xT,
                                          const float* __restrict__ conv_w, const float* __restrict__ dt_w,
                                          const float* __restrict__ A, const float* __restrict__ Dv,
                                          const float* __restrict__ g1w, const float* __restrict__ g2w,
                                          short* __restrict__ wf, short* __restrict__ wdtf,
                                          float* __restrict__ An, float* __restrict__ An2, float* __restrict__ Dp,
                                          float* __restrict__ pooled, float* __restrict__ g1wT, float* __restrict__ g2wT) {
    __shared__ float lt[64][65];
    int bid = blockIdx.x;
    int tid = threadIdx.x;
    if (bid < 2048) {
        int b = bid >> 7, rem = bid & 127;
        int tt = rem >> 1, ct = rem & 1;
        int t0 = tt * 64, c0 = ct * 64;
        int colr = tid & 63, rowb = tid >> 6;
#pragma unroll
        for (int r = 0; r < 16; ++r) {
            int row = rowb + r * 4;
            lt[row][colr] = x[(size_t)(b * CC + c0 + row) * LL + t0 + colr];
        }
        __syncthreads();
#pragma unroll
        for (int r = 0; r < 16; ++r) {
            int trow = rowb + r * 4;
            xT[((size_t)b * LL + t0 + trow) * CC + c0 + colr] = f2bf(lt[colr][trow]);
        }
        return;
    }
    int idx = (bid - 2048) * 256 + tid;
    if (idx < 18432) {
        int lane = idx & 63, fr = idx >> 6;
        int nfg = fr & 7, ks = (fr >> 3) & 3, tp = fr >> 5;
        int dy = tp / 3, dx = tp % 3;
        int cout = nfg * 16 + (lane & 15);
        int cin0 = ks * 32 + (lane >> 4) * 8;
        short8 v;
#pragma unroll
        for (int j = 0; j < 8; ++j)
            v[j] = (short)f2bf(conv_w[((cout * CC + cin0 + j) * 3 + dy) * 3 + dx]);
        *(short8*)(wf + (size_t)idx * 8) = v;
    } else if (idx < 20480) {
        int i2 = idx - 18432;
        int lane = i2 & 63, fr = i2 >> 6;
        int nfg = fr & 7, ks = fr >> 3;
        int o = nfg * 16 + (lane & 15);
        int c0 = ks * 32 + (lane >> 4) * 8;
        short8 v;
#pragma unroll
        for (int j = 0; j < 8; ++j) v[j] = (short)f2bf(dt_w[o * CC + c0 + j]);
        *(short8*)(wdtf + (size_t)i2 * 8) = v;
    } else if (idx < 22528) {
        int i3 = idx - 20480;
        float a = -expf(A[i3]);
        An[i3] = a;
        An2[i3] = a * 1.4426950408889634f;
    } else if (idx < 22656) {
        int c = idx - 22528;
        Dp[c] = expf(Dv[c]);
    } else if (idx < 24704) {
        pooled[idx - 22656] = 0.f;
    } else if (idx < 41088) {
        int i = idx - 24704;
        int c = i >> 7, o = i & 127;
        g1wT[i] = g1w[o * 128 + c];
    } else if (idx < 57472) {
        int i = idx - 41088;
        int c = i >> 7, o = i & 127;
        g2wT[i] = g2w[o * 128 + c];
    }
}

// ---------------- K1: 3x3 conv via MFMA implicit GEMM ----------------
__global__ __launch_bounds__(256) void k1(const unsigned short* __restrict__ xT,
                                          const short* __restrict__ wf,
                                          const float* __restrict__ conv_b,
                                          unsigned short* __restrict__ convT,
                                          float* __restrict__ pooled) {
    __shared__ __align__(16) unsigned short slab[3 * 66 * 128];  // 50688 B
    int bid = blockIdx.x;
    int b = bid >> 6, h = bid & 63;
    int tid = threadIdx.x;
    int wave = tid >> 6, lane = tid & 63;

    if (tid < 96) {
        int dy = tid >> 5, r = (tid >> 4) & 1, j = tid & 15;
        u32x4 z = {0, 0, 0, 0};
        *(u32x4*)((char*)slab + dy * 16896 + (r ? 16640 : 0) + j * 16) = z;
    }
#pragma unroll
    for (int dy = 0; dy < 3; ++dy) {
        int hs = h + dy - 1;
        char* slabdy = (char*)slab + dy * 16896;
        if (hs >= 0 && hs < HH) {
            const char* src = (const char*)xT + (size_t)(b * LL + hs * 64) * 256;
#pragma unroll
            for (int i = 0; i < 4; ++i) {
                unsigned int Xbase = 256u + (unsigned)i * 4096u + (unsigned)wave * 1024u;
                unsigned int X = Xbase + (unsigned)lane * 16u;
                unsigned int tok = X >> 8;
                unsigned int srcoff = ((X & ~255u) - 256u) | ((X & 255u) ^ ((tok & 7u) << 4));
                __builtin_amdgcn_global_load_lds((const AS1 unsigned int*)(src + srcoff),
                                                 (AS3 unsigned int*)(slabdy + Xbase), 16, 0, 0);
            }
        } else {
            u32x4 z = {0, 0, 0, 0};
#pragma unroll
            for (int i = 0; i < 4; ++i)
                *(u32x4*)(slabdy + 256 + tid * 64 + i * 16) = z;
        }
    }
    __syncthreads();

    int lm = lane & 15, lg = lane >> 4;
    f32x4 acc[4][2];
#pragma unroll
    for (int m = 0; m < 4; ++m)
#pragma unroll
        for (int n = 0; n < 2; ++n) acc[m][n] = (f32x4){0.f, 0.f, 0.f, 0.f};

#pragma unroll
    for (int tp = 0; tp < 9; ++tp) {
        int dy = tp / 3, dx = tp % 3;
        const char* slabdy = (const char*)slab + dy * 16896;
#pragma unroll
        for (int ks = 0; ks < 4; ++ks) {
            short8 bf0 = *(const short8*)(wf + ((size_t)(((tp * 4 + ks) * 8) + wave * 2 + 0) * 64 + lane) * 8);
            short8 bf1 = *(const short8*)(wf + ((size_t)(((tp * 4 + ks) * 8) + wave * 2 + 1) * 64 + lane) * 8);
#pragma unroll
            for (int mf = 0; mf < 4; ++mf) {
                int tok = mf * 16 + lm + dx;
                unsigned int off = (unsigned)((tok * 256 + ks * 64 + lg * 16) ^ ((tok & 7) << 4));
                short8 af = *(const short8*)(slabdy + off);
                acc[mf][0] = __builtin_amdgcn_mfma_f32_16x16x32_bf16(af, bf0, acc[mf][0], 0, 0, 0);
                acc[mf][1] = __builtin_amdgcn_mfma_f32_16x16x32_bf16(af, bf1, acc[mf][1], 0, 0, 0);
            }
        }
    }

    int n0w = wave * 32;
    size_t tokbase = (size_t)(b * LL + h * 64);
    float psum[2] = {0.f, 0.f};
#pragma unroll
    for (int nf = 0; nf < 2; ++nf) {
        int n = n0w + nf * 16 + lm;
        float bias = conv_b[n];
#pragma unroll
        for (int mf = 0; mf < 4; ++mf)
#pragma unroll
            for (int r = 0; r < 4; ++r) {
                int w = mf * 16 + lg * 4 + r;
                float v = acc[mf][nf][r] + bias;
                convT[(tokbase + w) * CC + n] = f2bf(v);
                psum[nf] += v;
            }
    }
#pragma unroll
    for (int nf = 0; nf < 2; ++nf) {
        float s = psum[nf];
        s += __shfl_xor(s, 16);
        s += __shfl_xor(s, 32);
        if (lane < 16) atomicAdd(&pooled[b * CC + n0w + nf * 16 + lane], s);
    }
}

// ---------------- K3: gate + dt GEMM + sigmoid + fused scan phase-1 (+optional packed xdt) ----------------
__global__ __launch_bounds__(256) void k3(const unsigned short* __restrict__ convT,
                                          const short* __restrict__ wdtf,
                                          const float* __restrict__ pooled,
                                          const float* __restrict__ g1wT, const float* __restrict__ g1b,
                                          const float* __restrict__ g2wT, const float* __restrict__ g2b,
                                          float* __restrict__ gate,
                                          const float* __restrict__ dt_b,
                                          const float* __restrict__ An2,
                                          unsigned short* __restrict__ dtT,
                                          unsigned int* __restrict__ xdt,
                                          float* __restrict__ hend, float* __restrict__ decay,
                                          int packed) {
    __shared__ __align__(16) unsigned short albuf[128 * 128];   // 32KB gated-x (swizzled)
    __shared__ __align__(16) unsigned short dtl[128 * 136];     // 34KB dt (stride-136)
    __shared__ float gl[128];
    float* meanr = (float*)dtl;        // alias: dead before dtl's first real use
    float* garr  = ((float*)dtl) + 128;
    int bid = blockIdx.x;
    int b = bid >> 5, tile = bid & 31, t0 = tile * 128;
    int tid = threadIdx.x;
    int wave = tid >> 6, lane = tid & 63;

    // per-block gate compute (deterministic, identical across tiles of same b)
    if (tid < 128) meanr[tid] = pooled[b * CC + tid] * (1.f / 4096.f);
    __syncthreads();
    if (tid < 128) {
        float acc = g1b[tid];
        for (int c = 0; c < 128; ++c) acc += meanr[c] * g1wT[c * 128 + tid];
        garr[tid] = fmaxf(acc, 0.f);
    }
    __syncthreads();
    if (tid < 128) {
        float acc2 = g2b[tid];
        for (int c = 0; c < 128; ++c) acc2 += garr[c] * g2wT[c * 128 + tid];
        float gv = __builtin_amdgcn_rcpf(1.f + fexp2(-1.4426950408889634f * acc2));
        gl[tid] = gv;
        if (tile == 0) gate[b * CC + tid] = gv;
    }
    __syncthreads();

    const char* srcb = (const char*)convT + (size_t)(b * LL + t0) * 256;
#pragma unroll
    for (int i = 0; i < 8; ++i) {
        unsigned int byteoff = (unsigned)((i * 256 + tid) * 16);
        unsigned int tok = byteoff >> 8;
        unsigned int inner = byteoff & 255u;
        int c8 = (int)(inner >> 1);
        short8 v = *(const short8*)(srcb + (size_t)tok * 256 + inner);
#pragma unroll
        for (int j = 0; j < 8; ++j) {
            float f = bf2f((unsigned short)v[j]) * gl[c8 + j];
            v[j] = (short)f2bf(f);
        }
        *(short8*)((char*)albuf + (byteoff ^ ((tok & 7u) << 4))) = v;
    }
    __syncthreads();

    int lm = lane & 15, lg = lane >> 4;
    f32x4 acc[8][2];
#pragma unroll
    for (int m = 0; m < 8; ++m)
#pragma unroll
        for (int n = 0; n < 2; ++n) acc[m][n] = (f32x4){0.f, 0.f, 0.f, 0.f};
#pragma unroll
    for (int ks = 0; ks < 4; ++ks) {
        short8 bf0 = *(const short8*)(wdtf + ((size_t)((ks * 8) + wave * 2 + 0) * 64 + lane) * 8);
        short8 bf1 = *(const short8*)(wdtf + ((size_t)((ks * 8) + wave * 2 + 1) * 64 + lane) * 8);
#pragma unroll
        for (int mf = 0; mf < 8; ++mf) {
            int tok = mf * 16 + lm;
            unsigned int off = (unsigned)((tok * 256 + ks * 64 + lg * 16) ^ ((tok & 7) << 4));
            short8 af = *(const short8*)((const char*)albuf + off);
            acc[mf][0] = __builtin_amdgcn_mfma_f32_16x16x32_bf16(af, bf0, acc[mf][0], 0, 0, 0);
            acc[mf][1] = __builtin_amdgcn_mfma_f32_16x16x32_bf16(af, bf1, acc[mf][1], 0, 0, 0);
        }
    }
    __syncthreads();
#pragma unroll
    for (int nf = 0; nf < 2; ++nf) {
        int o = wave * 32 + nf * 16 + lm;
        float zb = dt_b[o];
#pragma unroll
        for (int mf = 0; mf < 8; ++mf)
#pragma unroll
            for (int r = 0; r < 4; ++r) {
                int tok = mf * 16 + lg * 4 + r;
                float z = acc[mf][nf][r] + zb;
                float d = __builtin_amdgcn_rcpf(1.f + fexp2(-1.4426950408889634f * z));
                unsigned short ub = f2bf(d);
                if (!packed) dtT[(size_t)(b * LL + t0 + tok) * CC + o] = ub;
                dtl[tok * 136 + o] = ub;
            }
    }
    __syncthreads();

    // fused scan phase-1: 2 chunks x 128 channels; x from albuf (gated), dt from dtl
    int half = tid >> 7, c = tid & 127;
    int ch = tile * 2 + half;
    float a2[SS], h[SS];
#pragma unroll
    for (int s = 0; s < SS; ++s) {
        a2[s] = An2[c * SS + s];
        h[s] = 0.f;
    }
    float sdt = 0.f;
    unsigned int* xdrow = xdt + ((size_t)b * CC + c) * LL + t0 + half * 64;
    for (int t4 = 0; t4 < 16; ++t4) {
        u32x4 pk;
#pragma unroll
        for (int j = 0; j < 4; ++j) {
            int t = t4 * 4 + j;
            int tokb = half * 64 + t;
            unsigned int xoff = ((unsigned)(tokb * 256 + c * 2)) ^ (((unsigned)tokb & 7u) << 4);
            unsigned short xu = *(const unsigned short*)((const char*)albuf + xoff);
            unsigned short du = dtl[tokb * 136 + c];
            float x = bf2f(xu);
            float d = bf2f(du);
            sdt += d;
#pragma unroll
            for (int s = 0; s < SS; ++s) h[s] = h[s] * fexp2(a2[s] * d) + x;
            pk[j] = (((unsigned int)du) << 16) | (unsigned int)xu;
        }
        if (packed) *(u32x4*)(xdrow + t4 * 4) = pk;
    }
    size_t base = ((size_t)(b * NCH + ch) * CC + c) * SS;
#pragma unroll
    for (int q = 0; q < 4; ++q) {
        f32x4 hv, dv;
#pragma unroll
        for (int j = 0; j < 4; ++j) {
            hv[j] = h[q * 4 + j];
            dv[j] = fexp2(a2[q * 4 + j] * sdt);
        }
        *(f32x4*)(hend + base + q * 4) = hv;
        *(f32x4*)(decay + base + q * 4) = dv;
    }
}

// ---------------- K5: sequential chunk combine ----------------
__global__ __launch_bounds__(256) void k5(const float* __restrict__ hend, const float* __restrict__ decay,
                                          float* __restrict__ H0) {
    int idx = blockIdx.x * 256 + threadIdx.x;  // 32768
    int b = idx >> 11, rem = idx & 2047;
    float Hv = 0.f;
    for (int k = 0; k < NCH; ++k) {
        size_t base = (size_t)(b * NCH + k) * 2048 + rem;
        H0[base] = Hv;
        Hv = hend[base] + Hv * decay[base];
    }
}

// ---------------- K6p: scan phase 2 from packed xdt [b][c][t], s-split, float2 math ----------------
__global__ __launch_bounds__(256, 4) void k6p(const unsigned int* __restrict__ xdt,
                                              const float* __restrict__ Antab,
                                              const float* __restrict__ An2tab,
                                              const float* __restrict__ Dp,
                                              const float* __restrict__ H0,
                                              const float* __restrict__ xin,
                                              float* __restrict__ out) {
    __shared__ unsigned short ylds[128][66];                // 16.9KB
    int bid = blockIdx.x;
    int b = bid >> 6, ch = bid & 63;
    int tid = threadIdx.x;                 // 256
    int wave = tid >> 6, lane = tid & 63;
    int t0 = ch * CT;
    int c = wave * 32 + (lane & 31);       // channel 0..127
    int shalf = lane >> 5;                 // 0: s=0..7, 1: s=8..15
    int s0 = shalf * 8;

    f32x2 a22[4], anv[4], h2[4];
#pragma unroll
    for (int q = 0; q < 2; ++q) {
        f32x4 av = *(const f32x4*)(An2tab + c * SS + s0 + q * 4);
        f32x4 nv = *(const f32x4*)(Antab + c * SS + s0 + q * 4);
        a22[q * 2 + 0] = (f32x2){av[0], av[1]};
        a22[q * 2 + 1] = (f32x2){av[2], av[3]};
        anv[q * 2 + 0] = (f32x2){nv[0], nv[1]};
        anv[q * 2 + 1] = (f32x2){nv[2], nv[3]};
    }
    size_t hbase = ((size_t)(b * NCH + ch) * CC + c) * SS + s0;
#pragma unroll
    for (int q = 0; q < 2; ++q) {
        f32x4 hv = *(const f32x4*)(H0 + hbase + q * 4);
        h2[q * 2 + 0] = (f32x2){hv[0], hv[1]};
        h2[q * 2 + 1] = (f32x2){hv[2], hv[3]};
    }
    float dpc = (shalf == 0) ? Dp[c] : 0.f;
    const u32x4* xdp = (const u32x4*)(xdt + ((size_t)b * CC + c) * LL + t0);

#pragma unroll 4
    for (int t4 = 0; t4 < 16; ++t4) {
        u32x4 w4 = xdp[t4];
#pragma unroll
        for (int j = 0; j < 4; ++j) {
            unsigned int w = w4[j];
            float x = asf(w << 16);            // gated x (bf16 in low half)
            float d = asf(w & 0xffff0000u);    // dt (bf16 in high half)
            f32x2 x2 = {x, x};
            f32x2 d2 = {d, d};
            f32x2 y2 = {0.f, 0.f};
#pragma unroll
            for (int q = 0; q < 4; ++q) {
                f32x2 tq = a22[q] * d2;
                f32x2 e2;
                e2.x = fexp2(tq.x);
                e2.y = fexp2(tq.y);
                h2[q] = h2[q] * e2 + x2;
                y2 += h2[q] * anv[q];
            }
            float yp = y2.x + y2.y + dpc * x;
            float yo = yp + __shfl_xor(yp, 32);
            if (shalf == 0) ylds[c][t4 * 4 + j] = f2bf(yo);
        }
    }
    __syncthreads();

    // coalesced output: each wave-quarter sweeps rows, lanes sweep 64 contiguous tokens
    int tt = tid & 63, wq = tid >> 6;
    size_t outbase = (size_t)b * CC * LL + t0 + tt;
#pragma unroll 4
    for (int rr = 0; rr < 32; ++rr) {
        int row = rr * 4 + wq;
        size_t gi = outbase + (size_t)row * LL;
        out[gi] = bf2f(ylds[row][tt]) + xin[gi];
    }
}

// ---------------- K6f: fallback (R7 version — strided u16 reads, gate applied here) ----------------
__global__ __launch_bounds__(256, 4) void k6f(const unsigned short* __restrict__ convT,
                                              const unsigned short* __restrict__ dtT,
                                              const float* __restrict__ gate,
                                              const float* __restrict__ Antab,
                                              const float* __restrict__ An2tab,
                                              const float* __restrict__ Dp,
                                              const float* __restrict__ H0,
                                              const float* __restrict__ xin,
                                              float* __restrict__ out) {
    __shared__ unsigned short ylds[128][66];
    int bid = blockIdx.x;
    int b = bid >> 6, ch = bid & 63;
    int tid = threadIdx.x;
    int wave = tid >> 6, lane = tid & 63;
    int t0 = ch * CT;
    int c = wave * 32 + (lane & 31);
    int shalf = lane >> 5;
    int s0 = shalf * 8;

    float a2[8], an[8], h[8];
#pragma unroll
    for (int q = 0; q < 2; ++q) {
        f32x4 av = *(const f32x4*)(An2tab + c * SS + s0 + q * 4);
        f32x4 nv = *(const f32x4*)(Antab + c * SS + s0 + q * 4);
#pragma unroll
        for (int j = 0; j < 4; ++j) { a2[q * 4 + j] = av[j]; an[q * 4 + j] = nv[j]; }
    }
    size_t hbase = ((size_t)(b * NCH + ch) * CC + c) * SS + s0;
#pragma unroll
    for (int q = 0; q < 2; ++q) {
        f32x4 hv = *(const f32x4*)(H0 + hbase + q * 4);
#pragma unroll
        for (int j = 0; j < 4; ++j) h[q * 4 + j] = hv[j];
    }
    float g = gate[b * CC + c];
    float dpc = (shalf == 0) ? Dp[c] : 0.f;
    const unsigned short* xp = convT + (size_t)(b * LL + t0) * CC + c;
    const unsigned short* dp = dtT + (size_t)(b * LL + t0) * CC + c;

#pragma unroll 4
    for (int t = 0; t < CT; ++t) {
        float x = bf2f(xp[t * CC]) * g;
        float d = bf2f(dp[t * CC]);
        float y0 = dpc * x, y1 = 0.f;
#pragma unroll
        for (int s = 0; s < 8; ++s) {
            h[s] = h[s] * fexp2(a2[s] * d) + x;
            if (s & 1) y1 += h[s] * an[s]; else y0 += h[s] * an[s];
        }
        float yp = y0 + y1;
        float yo = yp + __shfl_xor(yp, 32);
        if (shalf == 0) ylds[c][t] = f2bf(yo);
    }
    __syncthreads();

    int tt = tid & 63, wq = tid >> 6;
    size_t outbase = (size_t)b * CC * LL + t0 + tt;
#pragma unroll 4
    for (int rr = 0; rr < 32; ++rr) {
        int row = rr * 4 + wq;
        size_t gi = outbase + (size_t)row * LL;
        out[gi] = bf2f(ylds[row][tt]) + xin[gi];
    }
}

extern "C" void kernel_launch(void* const* d_in, const int* in_sizes, int n_in,
                              void* d_out, int out_size, void* d_ws, size_t ws_size,
                              hipStream_t stream) {
    const float* x      = (const float*)d_in[0];
    const float* conv_w = (const float*)d_in[1];
    const float* conv_b = (const float*)d_in[2];
    const float* dt_w   = (const float*)d_in[3];
    const float* dt_b   = (const float*)d_in[4];
    const float* A      = (const float*)d_in[5];
    const float* D      = (const float*)d_in[6];
    const float* g1w    = (const float*)d_in[7];
    const float* g1b    = (const float*)d_in[8];
    const float* g2w    = (const float*)d_in[9];
    const float* g2b    = (const float*)d_in[10];
    float* outp         = (float*)d_out;
    char* ws = (char*)d_ws;

    const bool P = (ws_size >= 67600896ull);   // packed-xdt path needs ~67.6MB

    unsigned short* xT;
    float *hend, *decay, *H0, *g1wT, *g2wT, *pooled, *gate, *Antab, *An2tab, *Dp;
    unsigned short *convT, *dtT;
    unsigned int* xdt;
    short *wf, *wdtf;

    if (P) {
        xT     = (unsigned short*)(ws + 0);          // k0->k1
        hend   = (float*)(ws + 0);                   // after k1 (overlays xT)
        decay  = (float*)(ws + 8388608);
        convT  = (unsigned short*)(ws + 16777216);   // k1->k3
        H0     = (float*)(ws + 16777216);            // k5->k6 (after k3 done w/ convT)
        xdt    = (unsigned int*)(ws + 33554432);     // 33.55MB, k3->k6p
        dtT    = (unsigned short*)(ws + 33554432);   // unused in P (k3 skips)
        wf     = (short*)(ws + 67108864);
        wdtf   = (short*)(ws + 67403776);
        pooled = (float*)(ws + 67436544);
        gate   = (float*)(ws + 67444736);
        Antab  = (float*)(ws + 67452928);
        An2tab = (float*)(ws + 67461120);
        Dp     = (float*)(ws + 67469312);
        g1wT   = (float*)(ws + 67469824);
        g2wT   = (float*)(ws + 67535360);
    } else {
        xT     = (unsigned short*)(ws + 0);
        hend   = (float*)(ws + 0);
        decay  = (float*)(ws + 8388608);
        convT  = (unsigned short*)(ws + 16777216);
        dtT    = (unsigned short*)(ws + 33554432);
        xdt    = (unsigned int*)(ws + 33554432);     // unused in F
        H0     = (float*)(ws + 50331648);
        g1wT   = (float*)(ws + 50331648);            // overlaid by H0 after k3
        g2wT   = (float*)(ws + 50397184);
        wf     = (short*)(ws + 58720256);
        wdtf   = (short*)(ws + 59015168);
        pooled = (float*)(ws + 59047936);
        gate   = (float*)(ws + 59056128);
        Antab  = (float*)(ws + 59064320);
        An2tab = (float*)(ws + 59072512);
        Dp     = (float*)(ws + 59080704);
    }

    hipLaunchKernelGGL(k0, dim3(2273), dim3(256), 0, stream, x, xT, conv_w, dt_w, A, D, g1w, g2w,
                       wf, wdtf, Antab, An2tab, Dp, pooled, g1wT, g2wT);
    hipLaunchKernelGGL(k1, dim3(1024), dim3(256), 0, stream, xT, wf, conv_b, convT, pooled);
    hipLaunchKernelGGL(k3, dim3(512), dim3(256), 0, stream, convT, wdtf, pooled, g1wT, g1b, g2wT, g2b,
                       gate, dt_b, An2tab, dtT, xdt, hend, decay, (int)P);
    hipLaunchKernelGGL(k5, dim3(128), dim3(256), 0, stream, hend, decay, H0);
    if (P) {
        hipLaunchKernelGGL(k6p, dim3(1024), dim3(256), 0, stream, (const unsigned int*)xdt,
                           Antab, An2tab, Dp, H0, x, outp);
    } else {
        hipLaunchKernelGGL(k6f, dim3(1024), dim3(256), 0, stream, convT, dtT, gate,
                           Antab, An2tab, Dp, H0, x, outp);
    }
}

// Round 10
// 120.327 us; speedup vs baseline: 1.0699x; 1.0101x over previous
//
#include <hip/hip_runtime.h>
#include <hip/hip_bf16.h>
#include <stdint.h>

#define BB 16
#define CC 128
#define HH 64
#define WW 64
#define LL 4096
#define SS 16
#define NCH 64
#define CT 64

typedef __attribute__((ext_vector_type(2))) float f32x2;
typedef __attribute__((ext_vector_type(4))) float f32x4;
typedef __attribute__((ext_vector_type(8))) short short8;
typedef __attribute__((ext_vector_type(4))) unsigned int u32x4;

#define AS1 __attribute__((address_space(1)))
#define AS3 __attribute__((address_space(3)))

__device__ __forceinline__ float bf2f(unsigned short u) {
    union { unsigned int i; float f; } v;
    v.i = ((unsigned int)u) << 16;
    return v.f;
}
__device__ __forceinline__ float asf(unsigned int u) {
    union { unsigned int i; float f; } v;
    v.i = u;
    return v.f;
}
__device__ __forceinline__ unsigned short f2bf(float f) {
    union { float f; unsigned int i; } v;
    v.f = f;
    unsigned int x = v.i;
    return (unsigned short)((x + 0x7fffu + ((x >> 16) & 1u)) >> 16);
}
__device__ __forceinline__ float fexp2(float x) { return __builtin_amdgcn_exp2f(x); }

// ---------------- K0: x-transpose (blocks 0..2047) + weight transforms (blocks 2048..) ----------------
__global__ __launch_bounds__(256) void k0(const float* __restrict__ x, unsigned short* __restrict__ xT,
                                          const float* __restrict__ conv_w, const float* __restrict__ dt_w,
                                          const float* __restrict__ A, const float* __restrict__ Dv,
                                          const float* __restrict__ g1w, const float* __restrict__ g2w,
                                          short* __restrict__ wf, short* __restrict__ wdtf,
                                          float* __restrict__ An, float* __restrict__ An2, float* __restrict__ Dp,
                                          float* __restrict__ pooled, float* __restrict__ g1wT, float* __restrict__ g2wT) {
    __shared__ float lt[64][65];
    int bid = blockIdx.x;
    int tid = threadIdx.x;
    if (bid < 2048) {
        int b = bid >> 7, rem = bid & 127;
        int tt = rem >> 1, ct = rem & 1;
        int t0 = tt * 64, c0 = ct * 64;
        int colr = tid & 63, rowb = tid >> 6;
#pragma unroll
        for (int r = 0; r < 16; ++r) {
            int row = rowb + r * 4;
            lt[row][colr] = x[(size_t)(b * CC + c0 + row) * LL + t0 + colr];
        }
        __syncthreads();
#pragma unroll
        for (int r = 0; r < 16; ++r) {
            int trow = rowb + r * 4;
            xT[((size_t)b * LL + t0 + trow) * CC + c0 + colr] = f2bf(lt[colr][trow]);
        }
        return;
    }
    int idx = (bid - 2048) * 256 + tid;
    if (idx < 18432) {
        int lane = idx & 63, fr = idx >> 6;
        int nfg = fr & 7, ks = (fr >> 3) & 3, tp = fr >> 5;
        int dy = tp / 3, dx = tp % 3;
        int cout = nfg * 16 + (lane & 15);
        int cin0 = ks * 32 + (lane >> 4) * 8;
        short8 v;
#pragma unroll
        for (int j = 0; j < 8; ++j)
            v[j] = (short)f2bf(conv_w[((cout * CC + cin0 + j) * 3 + dy) * 3 + dx]);
        *(short8*)(wf + (size_t)idx * 8) = v;
    } else if (idx < 20480) {
        int i2 = idx - 18432;
        int lane = i2 & 63, fr = i2 >> 6;
        int nfg = fr & 7, ks = fr >> 3;
        int o = nfg * 16 + (lane & 15);
        int c0 = ks * 32 + (lane >> 4) * 8;
        short8 v;
#pragma unroll
        for (int j = 0; j < 8; ++j) v[j] = (short)f2bf(dt_w[o * CC + c0 + j]);
        *(short8*)(wdtf + (size_t)i2 * 8) = v;
    } else if (idx < 22528) {
        int i3 = idx - 20480;
        float a = -expf(A[i3]);
        An[i3] = a;
        An2[i3] = a * 1.4426950408889634f;
    } else if (idx < 22656) {
        int c = idx - 22528;
        Dp[c] = expf(Dv[c]);
    } else if (idx < 24704) {
        pooled[idx - 22656] = 0.f;
    } else if (idx < 41088) {
        int i = idx - 24704;
        int c = i >> 7, o = i & 127;
        g1wT[i] = g1w[o * 128 + c];
    } else if (idx < 57472) {
        int i = idx - 41088;
        int c = i >> 7, o = i & 127;
        g2wT[i] = g2w[o * 128 + c];
    }
}

// ---------------- K1: 3x3 conv via MFMA implicit GEMM ----------------
__global__ __launch_bounds__(256) void k1(const unsigned short* __restrict__ xT,
                                          const short* __restrict__ wf,
                                          const float* __restrict__ conv_b,
                                          unsigned short* __restrict__ convT,
                                          float* __restrict__ pooled) {
    __shared__ __align__(16) unsigned short slab[3 * 66 * 128];  // 50688 B
    int bid = blockIdx.x;
    int b = bid >> 6, h = bid & 63;
    int tid = threadIdx.x;
    int wave = tid >> 6, lane = tid & 63;

    if (tid < 96) {
        int dy = tid >> 5, r = (tid >> 4) & 1, j = tid & 15;
        u32x4 z = {0, 0, 0, 0};
        *(u32x4*)((char*)slab + dy * 16896 + (r ? 16640 : 0) + j * 16) = z;
    }
#pragma unroll
    for (int dy = 0; dy < 3; ++dy) {
        int hs = h + dy - 1;
        char* slabdy = (char*)slab + dy * 16896;
        if (hs >= 0 && hs < HH) {
            const char* src = (const char*)xT + (size_t)(b * LL + hs * 64) * 256;
#pragma unroll
            for (int i = 0; i < 4; ++i) {
                unsigned int Xbase = 256u + (unsigned)i * 4096u + (unsigned)wave * 1024u;
                unsigned int X = Xbase + (unsigned)lane * 16u;
                unsigned int tok = X >> 8;
                unsigned int srcoff = ((X & ~255u) - 256u) | ((X & 255u) ^ ((tok & 7u) << 4));
                __builtin_amdgcn_global_load_lds((const AS1 unsigned int*)(src + srcoff),
                                                 (AS3 unsigned int*)(slabdy + Xbase), 16, 0, 0);
            }
        } else {
            u32x4 z = {0, 0, 0, 0};
#pragma unroll
            for (int i = 0; i < 4; ++i)
                *(u32x4*)(slabdy + 256 + tid * 64 + i * 16) = z;
        }
    }
    __syncthreads();

    int lm = lane & 15, lg = lane >> 4;
    f32x4 acc[4][2];
#pragma unroll
    for (int m = 0; m < 4; ++m)
#pragma unroll
        for (int n = 0; n < 2; ++n) acc[m][n] = (f32x4){0.f, 0.f, 0.f, 0.f};

#pragma unroll
    for (int tp = 0; tp < 9; ++tp) {
        int dy = tp / 3, dx = tp % 3;
        const char* slabdy = (const char*)slab + dy * 16896;
#pragma unroll
        for (int ks = 0; ks < 4; ++ks) {
            short8 bf0 = *(const short8*)(wf + ((size_t)(((tp * 4 + ks) * 8) + wave * 2 + 0) * 64 + lane) * 8);
            short8 bf1 = *(const short8*)(wf + ((size_t)(((tp * 4 + ks) * 8) + wave * 2 + 1) * 64 + lane) * 8);
#pragma unroll
            for (int mf = 0; mf < 4; ++mf) {
                int tok = mf * 16 + lm + dx;
                unsigned int off = (unsigned)((tok * 256 + ks * 64 + lg * 16) ^ ((tok & 7) << 4));
                short8 af = *(const short8*)(slabdy + off);
                acc[mf][0] = __builtin_amdgcn_mfma_f32_16x16x32_bf16(af, bf0, acc[mf][0], 0, 0, 0);
                acc[mf][1] = __builtin_amdgcn_mfma_f32_16x16x32_bf16(af, bf1, acc[mf][1], 0, 0, 0);
            }
        }
    }

    int n0w = wave * 32;
    size_t tokbase = (size_t)(b * LL + h * 64);
    float psum[2] = {0.f, 0.f};
#pragma unroll
    for (int nf = 0; nf < 2; ++nf) {
        int n = n0w + nf * 16 + lm;
        float bias = conv_b[n];
#pragma unroll
        for (int mf = 0; mf < 4; ++mf)
#pragma unroll
            for (int r = 0; r < 4; ++r) {
                int w = mf * 16 + lg * 4 + r;
                float v = acc[mf][nf][r] + bias;
                convT[(tokbase + w) * CC + n] = f2bf(v);
                psum[nf] += v;
            }
    }
#pragma unroll
    for (int nf = 0; nf < 2; ++nf) {
        float s = psum[nf];
        s += __shfl_xor(s, 16);
        s += __shfl_xor(s, 32);
        if (lane < 16) atomicAdd(&pooled[b * CC + n0w + nf * 16 + lane], s);
    }
}

// ---------------- K3: gate + dt GEMM + sigmoid + fused scan phase-1 (+optional packed xdt) ----------------
__global__ __launch_bounds__(256) void k3(const unsigned short* __restrict__ convT,
                                          const short* __restrict__ wdtf,
                                          const float* __restrict__ pooled,
                                          const float* __restrict__ g1wT, const float* __restrict__ g1b,
                                          const float* __restrict__ g2wT, const float* __restrict__ g2b,
                                          float* __restrict__ gate,
                                          const float* __restrict__ dt_b,
                                          const float* __restrict__ An2,
                                          unsigned short* __restrict__ dtT,
                                          unsigned int* __restrict__ xdt,
                                          float* __restrict__ hend, float* __restrict__ decay,
                                          int packed) {
    __shared__ __align__(16) unsigned short albuf[128 * 128];   // 32KB gated-x (swizzled)
    __shared__ __align__(16) unsigned short dtl[128 * 136];     // 34KB dt (stride-136)
    __shared__ float gl[128];
    float* meanr = (float*)dtl;        // alias: dead before dtl's first real use
    float* garr  = ((float*)dtl) + 128;
    int bid = blockIdx.x;
    int b = bid >> 5, tile = bid & 31, t0 = tile * 128;
    int tid = threadIdx.x;
    int wave = tid >> 6, lane = tid & 63;

    // per-block gate compute (deterministic, identical across tiles of same b)
    if (tid < 128) meanr[tid] = pooled[b * CC + tid] * (1.f / 4096.f);
    __syncthreads();
    if (tid < 128) {
        float acc = g1b[tid];
        for (int c = 0; c < 128; ++c) acc += meanr[c] * g1wT[c * 128 + tid];
        garr[tid] = fmaxf(acc, 0.f);
    }
    __syncthreads();
    if (tid < 128) {
        float acc2 = g2b[tid];
        for (int c = 0; c < 128; ++c) acc2 += garr[c] * g2wT[c * 128 + tid];
        float gv = __builtin_amdgcn_rcpf(1.f + fexp2(-1.4426950408889634f * acc2));
        gl[tid] = gv;
        if (tile == 0) gate[b * CC + tid] = gv;
    }
    __syncthreads();

    const char* srcb = (const char*)convT + (size_t)(b * LL + t0) * 256;
#pragma unroll
    for (int i = 0; i < 8; ++i) {
        unsigned int byteoff = (unsigned)((i * 256 + tid) * 16);
        unsigned int tok = byteoff >> 8;
        unsigned int inner = byteoff & 255u;
        int c8 = (int)(inner >> 1);
        short8 v = *(const short8*)(srcb + (size_t)tok * 256 + inner);
#pragma unroll
        for (int j = 0; j < 8; ++j) {
            float f = bf2f((unsigned short)v[j]) * gl[c8 + j];
            v[j] = (short)f2bf(f);
        }
        *(short8*)((char*)albuf + (byteoff ^ ((tok & 7u) << 4))) = v;
    }
    __syncthreads();

    int lm = lane & 15, lg = lane >> 4;
    f32x4 acc[8][2];
#pragma unroll
    for (int m = 0; m < 8; ++m)
#pragma unroll
        for (int n = 0; n < 2; ++n) acc[m][n] = (f32x4){0.f, 0.f, 0.f, 0.f};
#pragma unroll
    for (int ks = 0; ks < 4; ++ks) {
        short8 bf0 = *(const short8*)(wdtf + ((size_t)((ks * 8) + wave * 2 + 0) * 64 + lane) * 8);
        short8 bf1 = *(const short8*)(wdtf + ((size_t)((ks * 8) + wave * 2 + 1) * 64 + lane) * 8);
#pragma unroll
        for (int mf = 0; mf < 8; ++mf) {
            int tok = mf * 16 + lm;
            unsigned int off = (unsigned)((tok * 256 + ks * 64 + lg * 16) ^ ((tok & 7) << 4));
            short8 af = *(const short8*)((const char*)albuf + off);
            acc[mf][0] = __builtin_amdgcn_mfma_f32_16x16x32_bf16(af, bf0, acc[mf][0], 0, 0, 0);
            acc[mf][1] = __builtin_amdgcn_mfma_f32_16x16x32_bf16(af, bf1, acc[mf][1], 0, 0, 0);
        }
    }
    __syncthreads();
#pragma unroll
    for (int nf = 0; nf < 2; ++nf) {
        int o = wave * 32 + nf * 16 + lm;
        float zb = dt_b[o];
#pragma unroll
        for (int mf = 0; mf < 8; ++mf)
#pragma unroll
            for (int r = 0; r < 4; ++r) {
                int tok = mf * 16 + lg * 4 + r;
                float z = acc[mf][nf][r] + zb;
                float d = __builtin_amdgcn_rcpf(1.f + fexp2(-1.4426950408889634f * z));
                unsigned short ub = f2bf(d);
                if (!packed) dtT[(size_t)(b * LL + t0 + tok) * CC + o] = ub;
                dtl[tok * 136 + o] = ub;
            }
    }
    __syncthreads();

    // fused scan phase-1: 2 chunks x 128 channels; x from albuf (gated), dt from dtl
    int half = tid >> 7, c = tid & 127;
    int ch = tile * 2 + half;
    float a2[SS], h[SS];
#pragma unroll
    for (int s = 0; s < SS; ++s) {
        a2[s] = An2[c * SS + s];
        h[s] = 0.f;
    }
    float sdt = 0.f;
    unsigned int* xdrow = xdt + ((size_t)b * CC + c) * LL + t0 + half * 64;
    for (int t4 = 0; t4 < 16; ++t4) {
        u32x4 pk;
#pragma unroll
        for (int j = 0; j < 4; ++j) {
            int t = t4 * 4 + j;
            int tokb = half * 64 + t;
            unsigned int xoff = ((unsigned)(tokb * 256 + c * 2)) ^ (((unsigned)tokb & 7u) << 4);
            unsigned short xu = *(const unsigned short*)((const char*)albuf + xoff);
            unsigned short du = dtl[tokb * 136 + c];
            float x = bf2f(xu);
            float d = bf2f(du);
            sdt += d;
#pragma unroll
            for (int s = 0; s < SS; ++s) h[s] = h[s] * fexp2(a2[s] * d) + x;
            pk[j] = (((unsigned int)du) << 16) | (unsigned int)xu;
        }
        if (packed) *(u32x4*)(xdrow + t4 * 4) = pk;
    }
    size_t base = ((size_t)(b * NCH + ch) * CC + c) * SS;
#pragma unroll
    for (int q = 0; q < 4; ++q) {
        f32x4 hv, dv;
#pragma unroll
        for (int j = 0; j < 4; ++j) {
            hv[j] = h[q * 4 + j];
            dv[j] = fexp2(a2[q * 4 + j] * sdt);
        }
        *(f32x4*)(hend + base + q * 4) = hv;
        *(f32x4*)(decay + base + q * 4) = dv;
    }
}

// ---------------- K5: sequential chunk combine ----------------
__global__ __launch_bounds__(256) void k5(const float* __restrict__ hend, const float* __restrict__ decay,
                                          float* __restrict__ H0) {
    int idx = blockIdx.x * 256 + threadIdx.x;  // 32768
    int b = idx >> 11, rem = idx & 2047;
    float Hv = 0.f;
    for (int k = 0; k < NCH; ++k) {
        size_t base = (size_t)(b * NCH + k) * 2048 + rem;
        H0[base] = Hv;
        Hv = hend[base] + Hv * decay[base];
    }
}

// ---------------- K6p: scan phase 2 from packed xdt [b][c][t], s-split, float2 math ----------------
__global__ __launch_bounds__(256, 4) void k6p(const unsigned int* __restrict__ xdt,
                                              const float* __restrict__ Antab,
                                              const float* __restrict__ An2tab,
                                              const float* __restrict__ Dp,
                                              const float* __restrict__ H0,
                                              const float* __restrict__ xin,
                                              float* __restrict__ out) {
    __shared__ unsigned short ylds[128][66];                // 16.9KB
    int bid = blockIdx.x;
    int b = bid >> 6, ch = bid & 63;
    int tid = threadIdx.x;                 // 256
    int wave = tid >> 6, lane = tid & 63;
    int t0 = ch * CT;
    int c = wave * 32 + (lane & 31);       // channel 0..127
    int shalf = lane >> 5;                 // 0: s=0..7, 1: s=8..15
    int s0 = shalf * 8;

    f32x2 a22[4], anv[4], h2[4];
#pragma unroll
    for (int q = 0; q < 2; ++q) {
        f32x4 av = *(const f32x4*)(An2tab + c * SS + s0 + q * 4);
        f32x4 nv = *(const f32x4*)(Antab + c * SS + s0 + q * 4);
        a22[q * 2 + 0] = (f32x2){av[0], av[1]};
        a22[q * 2 + 1] = (f32x2){av[2], av[3]};
        anv[q * 2 + 0] = (f32x2){nv[0], nv[1]};
        anv[q * 2 + 1] = (f32x2){nv[2], nv[3]};
    }
    size_t hbase = ((size_t)(b * NCH + ch) * CC + c) * SS + s0;
#pragma unroll
    for (int q = 0; q < 2; ++q) {
        f32x4 hv = *(const f32x4*)(H0 + hbase + q * 4);
        h2[q * 2 + 0] = (f32x2){hv[0], hv[1]};
        h2[q * 2 + 1] = (f32x2){hv[2], hv[3]};
    }
    float dpc = (shalf == 0) ? Dp[c] : 0.f;
    const u32x4* xdp = (const u32x4*)(xdt + ((size_t)b * CC + c) * LL + t0);

#pragma unroll 4
    for (int t4 = 0; t4 < 16; ++t4) {
        u32x4 w4 = xdp[t4];
#pragma unroll
        for (int j = 0; j < 4; ++j) {
            unsigned int w = w4[j];
            float x = asf(w << 16);            // gated x (bf16 in low half)
            float d = asf(w & 0xffff0000u);    // dt (bf16 in high half)
            f32x2 x2 = {x, x};
            f32x2 d2 = {d, d};
            f32x2 y2 = {0.f, 0.f};
#pragma unroll
            for (int q = 0; q < 4; ++q) {
                f32x2 tq = a22[q] * d2;
                f32x2 e2;
                e2.x = fexp2(tq.x);
                e2.y = fexp2(tq.y);
                h2[q] = h2[q] * e2 + x2;
                y2 += h2[q] * anv[q];
            }
            float yp = y2.x + y2.y + dpc * x;
            float yo = yp + __shfl_xor(yp, 32);
            if (shalf == 0) ylds[c][t4 * 4 + j] = f2bf(yo);
        }
    }
    __syncthreads();

    // coalesced output: each wave-quarter sweeps rows, lanes sweep 64 contiguous tokens
    int tt = tid & 63, wq = tid >> 6;
    size_t outbase = (size_t)b * CC * LL + t0 + tt;
#pragma unroll 4
    for (int rr = 0; rr < 32; ++rr) {
        int row = rr * 4 + wq;
        size_t gi = outbase + (size_t)row * LL;
        out[gi] = bf2f(ylds[row][tt]) + xin[gi];
    }
}

// ---------------- K6f: fallback (R7 version — strided u16 reads, gate applied here) ----------------
__global__ __launch_bounds__(256, 4) void k6f(const unsigned short* __restrict__ convT,
                                              const unsigned short* __restrict__ dtT,
                                              const float* __restrict__ gate,
                                              const float* __restrict__ Antab,
                                              const float* __restrict__ An2tab,
                                              const float* __restrict__ Dp,
                                              const float* __restrict__ H0,
                                              const float* __restrict__ xin,
                                              float* __restrict__ out) {
    __shared__ unsigned short ylds[128][66];
    int bid = blockIdx.x;
    int b = bid >> 6, ch = bid & 63;
    int tid = threadIdx.x;
    int wave = tid >> 6, lane = tid & 63;
    int t0 = ch * CT;
    int c = wave * 32 + (lane & 31);
    int shalf = lane >> 5;
    int s0 = shalf * 8;

    float a2[8], an[8], h[8];
#pragma unroll
    for (int q = 0; q < 2; ++q) {
        f32x4 av = *(const f32x4*)(An2tab + c * SS + s0 + q * 4);
        f32x4 nv = *(const f32x4*)(Antab + c * SS + s0 + q * 4);
#pragma unroll
        for (int j = 0; j < 4; ++j) { a2[q * 4 + j] = av[j]; an[q * 4 + j] = nv[j]; }
    }
    size_t hbase = ((size_t)(b * NCH + ch) * CC + c) * SS + s0;
#pragma unroll
    for (int q = 0; q < 2; ++q) {
        f32x4 hv = *(const f32x4*)(H0 + hbase + q * 4);
#pragma unroll
        for (int j = 0; j < 4; ++j) h[q * 4 + j] = hv[j];
    }
    float g = gate[b * CC + c];
    float dpc = (shalf == 0) ? Dp[c] : 0.f;
    const unsigned short* xp = convT + (size_t)(b * LL + t0) * CC + c;
    const unsigned short* dp = dtT + (size_t)(b * LL + t0) * CC + c;

#pragma unroll 4
    for (int t = 0; t < CT; ++t) {
        float x = bf2f(xp[t * CC]) * g;
        float d = bf2f(dp[t * CC]);
        float y0 = dpc * x, y1 = 0.f;
#pragma unroll
        for (int s = 0; s < 8; ++s) {
            h[s] = h[s] * fexp2(a2[s] * d) + x;
            if (s & 1) y1 += h[s] * an[s]; else y0 += h[s] * an[s];
        }
        float yp = y0 + y1;
        float yo = yp + __shfl_xor(yp, 32);
        if (shalf == 0) ylds[c][t] = f2bf(yo);
    }
    __syncthreads();

    int tt = tid & 63, wq = tid >> 6;
    size_t outbase = (size_t)b * CC * LL + t0 + tt;
#pragma unroll 4
    for (int rr = 0; rr < 32; ++rr) {
        int row = rr * 4 + wq;
        size_t gi = outbase + (size_t)row * LL;
        out[gi] = bf2f(ylds[row][tt]) + xin[gi];
    }
}

extern "C" void kernel_launch(void* const* d_in, const int* in_sizes, int n_in,
                              void* d_out, int out_size, void* d_ws, size_t ws_size,
                              hipStream_t stream) {
    const float* x      = (const float*)d_in[0];
    const float* conv_w = (const float*)d_in[1];
    const float* conv_b = (const float*)d_in[2];
    const float* dt_w   = (const float*)d_in[3];
    const float* dt_b   = (const float*)d_in[4];
    const float* A      = (const float*)d_in[5];
    const float* D      = (const float*)d_in[6];
    const float* g1w    = (const float*)d_in[7];
    const float* g1b    = (const float*)d_in[8];
    const float* g2w    = (const float*)d_in[9];
    const float* g2b    = (const float*)d_in[10];
    float* outp         = (float*)d_out;
    char* ws = (char*)d_ws;

    const bool P = (ws_size >= 67600896ull);   // packed-xdt path needs ~67.6MB

    unsigned short* xT;
    float *hend, *decay, *H0, *g1wT, *g2wT, *pooled, *gate, *Antab, *An2tab, *Dp;
    unsigned short *convT, *dtT;
    unsigned int* xdt;
    short *wf, *wdtf;

    if (P) {
        xT     = (unsigned short*)(ws + 0);          // k0->k1
        hend   = (float*)(ws + 0);                   // after k1 (overlays xT)
        decay  = (float*)(ws + 8388608);
        convT  = (unsigned short*)(ws + 16777216);   // k1->k3
        H0     = (float*)(ws + 16777216);            // k5->k6 (after k3 done w/ convT)
        xdt    = (unsigned int*)(ws + 33554432);     // 33.55MB, k3->k6p
        dtT    = (unsigned short*)(ws + 33554432);   // unused in P (k3 skips)
        wf     = (short*)(ws + 67108864);
        wdtf   = (short*)(ws + 67403776);
        pooled = (float*)(ws + 67436544);
        gate   = (float*)(ws + 67444736);
        Antab  = (float*)(ws + 67452928);
        An2tab = (float*)(ws + 67461120);
        Dp     = (float*)(ws + 67469312);
        g1wT   = (float*)(ws + 67469824);
        g2wT   = (float*)(ws + 67535360);
    } else {
        xT     = (unsigned short*)(ws + 0);
        hend   = (float*)(ws + 0);
        decay  = (float*)(ws + 8388608);
        convT  = (unsigned short*)(ws + 16777216);
        dtT    = (unsigned short*)(ws + 33554432);
        xdt    = (unsigned int*)(ws + 33554432);     // unused in F
        H0     = (float*)(ws + 50331648);
        g1wT   = (float*)(ws + 50331648);            // overlaid by H0 after k3
        g2wT   = (float*)(ws + 50397184);
        wf     = (short*)(ws + 58720256);
        wdtf   = (short*)(ws + 59015168);
        pooled = (float*)(ws + 59047936);
        gate   = (float*)(ws + 59056128);
        Antab  = (float*)(ws + 59064320);
        An2tab = (float*)(ws + 59072512);
        Dp     = (float*)(ws + 59080704);
    }

    hipLaunchKernelGGL(k0, dim3(2273), dim3(256), 0, stream, x, xT, conv_w, dt_w, A, D, g1w, g2w,
                       wf, wdtf, Antab, An2tab, Dp, pooled, g1wT, g2wT);
    hipLaunchKernelGGL(k1, dim3(1024), dim3(256), 0, stream, xT, wf, conv_b, convT, pooled);
    hipLaunchKernelGGL(k3, dim3(512), dim3(256), 0, stream, convT, wdtf, pooled, g1wT, g1b, g2wT, g2b,
                       gate, dt_b, An2tab, dtT, xdt, hend, decay, (int)P);
    hipLaunchKernelGGL(k5, dim3(128), dim3(256), 0, stream, hend, decay, H0);
    if (P) {
        hipLaunchKernelGGL(k6p, dim3(1024), dim3(256), 0, stream, (const unsigned int*)xdt,
                           Antab, An2tab, Dp, H0, x, outp);
    } else {
        hipLaunchKernelGGL(k6f, dim3(1024), dim3(256), 0, stream, convT, dtT, gate,
                           Antab, An2tab, Dp, H0, x, outp);
    }
}